// Round 1
// baseline (1176.828 us; speedup 1.0000x reference)
//
#include <hip/hip_runtime.h>

#define IMG_H 512
#define IMG_W 512
#define VIEW_TAN_F 0.57735026918962576451f  // tan(30 deg)
#define NEARZ 0.1f
#define BIGF 1e10f

// Per-face data: 3 x float4 = {A0,B0,C0,A1},{B1,C1,A2,B2},{C2,Az,Bz,Cz}
// Edge coefficients premultiplied by sign(area): inside <=> w0,w1,w2 >= 0.
// z = Az*x + Bz*y + Cz (affine; division by area folded into coefficients).

__global__ void prep_faces(const float* __restrict__ verts,
                           const int* __restrict__ faces,
                           const float* __restrict__ tex,
                           const float* __restrict__ campos,
                           const float* __restrict__ camup,
                           float4* __restrict__ fd,
                           float* __restrict__ cols,
                           int F)
{
    int f = blockIdx.x * blockDim.x + threadIdx.x;
    if (f >= F) return;

    float ex = campos[0], ey = campos[1], ez = campos[2];
    float ux = camup[0], uy = camup[1], uz = camup[2];
    // z_axis = normalize(-eye)
    float zxv = -ex, zyv = -ey, zzv = -ez;
    float inv = 1.0f / (sqrtf(zxv*zxv + zyv*zyv + zzv*zzv) + 1e-12f);
    zxv *= inv; zyv *= inv; zzv *= inv;
    // normalize(up)
    inv = 1.0f / (sqrtf(ux*ux + uy*uy + uz*uz) + 1e-12f);
    ux *= inv; uy *= inv; uz *= inv;
    // x_axis = normalize(cross(up_n, z_axis))
    float xxv = uy*zzv - uz*zyv;
    float xyv = uz*zxv - ux*zzv;
    float xzv = ux*zyv - uy*zxv;
    inv = 1.0f / (sqrtf(xxv*xxv + xyv*xyv + xzv*xzv) + 1e-12f);
    xxv *= inv; xyv *= inv; xzv *= inv;
    // y_axis = cross(z_axis, x_axis)
    float yxv = zyv*xzv - zzv*xyv;
    float yyv = zzv*xxv - zxv*xzv;
    float yzv = zxv*xyv - zyv*xxv;

    float px_[3], py_[3], pz_[3];
    #pragma unroll
    for (int k = 0; k < 3; ++k) {
        int vi = faces[f*3 + k];
        float vx = verts[vi*3+0] - ex;
        float vy = verts[vi*3+1] - ey;
        float vz = verts[vi*3+2] - ez;
        float cx = xxv*vx + xyv*vy + xzv*vz;
        float cy = yxv*vx + yyv*vy + yzv*vz;
        float cz = zxv*vx + zyv*vy + zzv*vz;
        float denom = cz * VIEW_TAN_F + 1e-12f;
        px_[k] = cx / denom;
        py_[k] = cy / denom;
        pz_[k] = cz;
    }
    float x0 = px_[0], y0 = py_[0];
    float x1 = px_[1], y1 = py_[1];
    float x2 = px_[2], y2 = py_[2];
    float area = (x1-x0)*(y2-y0) - (y1-y0)*(x2-x0);
    bool valid = fabsf(area) > 1e-8f;
    float safe = valid ? area : 1.0f;
    float s = (area > 0.0f) ? 1.0f : -1.0f;

    float A0 = -(y2-y1), B0 = (x2-x1), C0 = (y2-y1)*x1 - (x2-x1)*y1;
    float A1 = -(y0-y2), B1 = (x0-x2), C1 = (y0-y2)*x2 - (x0-x2)*y2;
    float A2 = -(y1-y0), B2 = (x1-x0), C2 = (y1-y0)*x0 - (x1-x0)*y0;

    float invs = 1.0f / safe;
    float Az = (A0*pz_[0] + A1*pz_[1] + A2*pz_[2]) * invs;
    float Bz = (B0*pz_[0] + B1*pz_[1] + B2*pz_[2]) * invs;
    float Cz = (C0*pz_[0] + C1*pz_[1] + C2*pz_[2]) * invs;

    // premultiply edges by sign -> inside test becomes w >= 0
    A0 *= s; B0 *= s; C0 *= s;
    A1 *= s; B1 *= s; C1 *= s;
    A2 *= s; B2 *= s; C2 *= s;

    if (!valid) {
        A0 = B0 = A1 = B1 = A2 = B2 = 0.0f;
        C0 = C1 = C2 = -1.0f;   // always fails inside test
        Az = Bz = 0.0f; Cz = 0.0f;
    }

    fd[f*3+0] = make_float4(A0, B0, C0, A1);
    fd[f*3+1] = make_float4(B1, C1, A2, B2);
    fd[f*3+2] = make_float4(C2, Az, Bz, Cz);

    // per-face mean color: mean over 8 texels, 3 channels
    float c0 = 0.0f, c1 = 0.0f, c2 = 0.0f;
    #pragma unroll
    for (int t = 0; t < 8; ++t) {
        c0 += tex[f*24 + t*3 + 0];
        c1 += tex[f*24 + t*3 + 1];
        c2 += tex[f*24 + t*3 + 2];
    }
    cols[f*3+0] = c0 * 0.125f;
    cols[f*3+1] = c1 * 0.125f;
    cols[f*3+2] = c2 * 0.125f;
}

__global__ __launch_bounds__(256) void raster_loss(
    const float4* __restrict__ fd,
    const float* __restrict__ cols,
    const float* __restrict__ imref,
    float* __restrict__ out, int F)
{
    int p = blockIdx.x * 256 + threadIdx.x;
    int row = p >> 9;              // W = 512
    int col = p & (IMG_W - 1);
    float x = ((float)col + 0.5f) * (2.0f / IMG_W) - 1.0f;
    float y = 1.0f - ((float)row + 0.5f) * (2.0f / IMG_H);

    float bestz = BIGF;
    int besti = -1;
    for (int f = 0; f < F; ++f) {
        float4 q0 = fd[3*f + 0];
        float4 q1 = fd[3*f + 1];
        float4 q2 = fd[3*f + 2];
        float w0 = fmaf(q0.x, x, fmaf(q0.y, y, q0.z));
        float w1 = fmaf(q0.w, x, fmaf(q1.x, y, q1.y));
        float w2 = fmaf(q1.z, x, fmaf(q1.w, y, q2.x));
        float z  = fmaf(q2.y, x, fmaf(q2.z, y, q2.w));
        bool hit = (w0 >= 0.0f) & (w1 >= 0.0f) & (w2 >= 0.0f) & (z > NEARZ);
        float zm = hit ? z : BIGF;
        if (zm < bestz) { bestz = zm; besti = f; }   // strict <: earliest face wins ties
    }

    float r = 0.0f, g = 0.0f, b = 0.0f;
    if (besti >= 0) {
        r = cols[besti*3+0];
        g = cols[besti*3+1];
        b = cols[besti*3+2];
    }

    // image[:, ::-1] reverses the CHANNEL axis: image[0,c] = color[..., 2-c]
    const int HW = IMG_H * IMG_W;
    float d0 = b - imref[0*HW + p];
    float d1 = g - imref[1*HW + p];
    float d2 = r - imref[2*HW + p];
    float loss = fmaf(d0, d0, fmaf(d1, d1, d2*d2));

    // wave (64) reduction
    #pragma unroll
    for (int off = 32; off > 0; off >>= 1)
        loss += __shfl_down(loss, off, 64);

    __shared__ float wsum[4];
    int wid  = threadIdx.x >> 6;
    int lane = threadIdx.x & 63;
    if (lane == 0) wsum[wid] = loss;
    __syncthreads();
    if (threadIdx.x == 0) {
        float bsum = wsum[0] + wsum[1] + wsum[2] + wsum[3];
        atomicAdd(out, bsum);
    }
}

extern "C" void kernel_launch(void* const* d_in, const int* in_sizes, int n_in,
                              void* d_out, int out_size, void* d_ws, size_t ws_size,
                              hipStream_t stream)
{
    const float* verts  = (const float*)d_in[0];
    const int*   faces  = (const int*)d_in[1];
    const float* tex    = (const float*)d_in[2];
    const float* campos = (const float*)d_in[3];
    const float* camup  = (const float*)d_in[4];
    const float* imref  = (const float*)d_in[5];
    int F = in_sizes[1] / 3;

    float4* fd   = (float4*)d_ws;
    float*  cols = (float*)((char*)d_ws + (size_t)F * 3 * sizeof(float4));
    float*  out  = (float*)d_out;

    hipMemsetAsync(d_out, 0, sizeof(float), stream);
    prep_faces<<<(F + 255)/256, 256, 0, stream>>>(verts, faces, tex, campos, camup, fd, cols, F);
    raster_loss<<<(IMG_H*IMG_W)/256, 256, 0, stream>>>(fd, cols, imref, out, F);
}

// Round 2
// 174.099 us; speedup vs baseline: 6.7595x; 6.7595x over previous
//
#include <hip/hip_runtime.h>

#define IMG_H 512
#define IMG_W 512
#define VIEW_TAN_F 0.57735026918962576451f  // tan(30 deg)
#define NEARZ 0.1f
#define BIGF 1e10f

#define TILE 32
#define NTX (IMG_W / TILE)      // 16 tiles per row
#define NTILES (NTX * NTX)      // 256 tiles
#define SPLITS 8                // face-range splits per tile
#define FCHUNK 256              // faces tested per compaction round

// Per-face data: 3 x float4 = {A0,B0,C0,A1},{B1,C1,A2,B2},{C2,Az,Bz,Cz}
// Edge coefficients premultiplied by sign(area): inside <=> w0,w1,w2 >= 0.
// z = Az*x + Bz*y + Cz (affine; division by area folded into coefficients).

__global__ void prep_faces(const float* __restrict__ verts,
                           const int* __restrict__ faces,
                           const float* __restrict__ tex,
                           const float* __restrict__ campos,
                           const float* __restrict__ camup,
                           float4* __restrict__ fd,
                           float* __restrict__ cols,
                           int F)
{
    int f = blockIdx.x * blockDim.x + threadIdx.x;
    if (f >= F) return;

    float ex = campos[0], ey = campos[1], ez = campos[2];
    float ux = camup[0], uy = camup[1], uz = camup[2];
    float zxv = -ex, zyv = -ey, zzv = -ez;
    float inv = 1.0f / (sqrtf(zxv*zxv + zyv*zyv + zzv*zzv) + 1e-12f);
    zxv *= inv; zyv *= inv; zzv *= inv;
    inv = 1.0f / (sqrtf(ux*ux + uy*uy + uz*uz) + 1e-12f);
    ux *= inv; uy *= inv; uz *= inv;
    float xxv = uy*zzv - uz*zyv;
    float xyv = uz*zxv - ux*zzv;
    float xzv = ux*zyv - uy*zxv;
    inv = 1.0f / (sqrtf(xxv*xxv + xyv*xyv + xzv*xzv) + 1e-12f);
    xxv *= inv; xyv *= inv; xzv *= inv;
    float yxv = zyv*xzv - zzv*xyv;
    float yyv = zzv*xxv - zxv*xzv;
    float yzv = zxv*xyv - zyv*xxv;

    float px_[3], py_[3], pz_[3];
    #pragma unroll
    for (int k = 0; k < 3; ++k) {
        int vi = faces[f*3 + k];
        float vx = verts[vi*3+0] - ex;
        float vy = verts[vi*3+1] - ey;
        float vz = verts[vi*3+2] - ez;
        float cx = xxv*vx + xyv*vy + xzv*vz;
        float cy = yxv*vx + yyv*vy + yzv*vz;
        float cz = zxv*vx + zyv*vy + zzv*vz;
        float denom = cz * VIEW_TAN_F + 1e-12f;
        px_[k] = cx / denom;
        py_[k] = cy / denom;
        pz_[k] = cz;
    }
    float x0 = px_[0], y0 = py_[0];
    float x1 = px_[1], y1 = py_[1];
    float x2 = px_[2], y2 = py_[2];
    float area = (x1-x0)*(y2-y0) - (y1-y0)*(x2-x0);
    bool valid = fabsf(area) > 1e-8f;
    float safe = valid ? area : 1.0f;
    float s = (area > 0.0f) ? 1.0f : -1.0f;

    float A0 = -(y2-y1), B0 = (x2-x1), C0 = (y2-y1)*x1 - (x2-x1)*y1;
    float A1 = -(y0-y2), B1 = (x0-x2), C1 = (y0-y2)*x2 - (x0-x2)*y2;
    float A2 = -(y1-y0), B2 = (x1-x0), C2 = (y1-y0)*x0 - (x1-x0)*y0;

    float invs = 1.0f / safe;
    float Az = (A0*pz_[0] + A1*pz_[1] + A2*pz_[2]) * invs;
    float Bz = (B0*pz_[0] + B1*pz_[1] + B2*pz_[2]) * invs;
    float Cz = (C0*pz_[0] + C1*pz_[1] + C2*pz_[2]) * invs;

    A0 *= s; B0 *= s; C0 *= s;
    A1 *= s; B1 *= s; C1 *= s;
    A2 *= s; B2 *= s; C2 *= s;

    if (!valid) {
        A0 = B0 = A1 = B1 = A2 = B2 = 0.0f;
        C0 = C1 = C2 = -1.0f;   // always fails inside + tile tests
        Az = Bz = 0.0f; Cz = 0.0f;
    }

    fd[f*3+0] = make_float4(A0, B0, C0, A1);
    fd[f*3+1] = make_float4(B1, C1, A2, B2);
    fd[f*3+2] = make_float4(C2, Az, Bz, Cz);

    float c0 = 0.0f, c1 = 0.0f, c2 = 0.0f;
    #pragma unroll
    for (int t = 0; t < 8; ++t) {
        c0 += tex[f*24 + t*3 + 0];
        c1 += tex[f*24 + t*3 + 1];
        c2 += tex[f*24 + t*3 + 2];
    }
    cols[f*3+0] = c0 * 0.125f;
    cols[f*3+1] = c1 * 0.125f;
    cols[f*3+2] = c2 * 0.125f;
}

// Tiled rasterizer: block = (tile, face-split). Conservative edge test vs the
// tile rectangle culls ~85% of faces; survivors compacted into LDS; 4 px/thread.
__global__ __launch_bounds__(256) void raster_tiled(
    const float4* __restrict__ fd, int F,
    unsigned long long* __restrict__ zbuf)
{
    __shared__ float4 sA[FCHUNK][3];
    __shared__ int    sF[FCHUNK];
    __shared__ int    sCnt;

    int b     = blockIdx.x;
    int split = b & (SPLITS - 1);
    int tile  = b >> 3;                  // log2(SPLITS)
    int tX = tile & (NTX - 1);
    int tY = tile >> 4;                  // log2(NTX)
    int tid  = threadIdx.x;
    int lane = tid & 63;

    int colp = tX * TILE + (tid & 31);
    int row0 = tY * TILE + (tid >> 5);   // rows row0 + 8k, k=0..3
    float x  = ((float)colp + 0.5f) * (2.0f / IMG_W) - 1.0f;
    float y0 = 1.0f - ((float)row0 + 0.5f) * (2.0f / IMG_H);

    float cx = ((float)(tX * TILE + 16)) * (2.0f / IMG_W) - 1.0f;
    float cy = 1.0f - ((float)(tY * TILE + 16)) * (2.0f / IMG_H);
    const float hx = 16.0f * (2.0f / IMG_W);   // 0.0625
    const float hy = 16.0f * (2.0f / IMG_H);

    float bz[4] = {BIGF, BIGF, BIGF, BIGF};
    int   bi[4] = {-1, -1, -1, -1};

    int fps = (F + SPLITS - 1) / SPLITS;          // faces per split
    int fbase = split * fps;
    int fend  = min(fbase + fps, F);
    for (int c0f = fbase; c0f < fend; c0f += FCHUNK) {
        int f = c0f + tid;
        float4 q0, q1, q2;
        bool pass = false;
        if (f < fend) {
            q0 = fd[3*f + 0];
            q1 = fd[3*f + 1];
            q2 = fd[3*f + 2];
            float e0 = fmaf(q0.x, cx, fmaf(q0.y, cy, q0.z)) + fabsf(q0.x)*hx + fabsf(q0.y)*hy;
            float e1 = fmaf(q0.w, cx, fmaf(q1.x, cy, q1.y)) + fabsf(q0.w)*hx + fabsf(q1.x)*hy;
            float e2 = fmaf(q1.z, cx, fmaf(q1.w, cy, q2.x)) + fabsf(q1.z)*hx + fabsf(q1.w)*hy;
            pass = fminf(fminf(e0, e1), e2) >= -1e-6f;
        }

        __syncthreads();                  // previous consume done
        if (tid == 0) sCnt = 0;
        __syncthreads();

        unsigned long long m = __ballot(pass);
        int wbase = 0;
        if (lane == 0 && m) wbase = atomicAdd(&sCnt, __popcll(m));
        wbase = __shfl(wbase, 0, 64);
        if (pass) {
            int pos = wbase + __popcll(m & ((1ull << lane) - 1ull));
            sA[pos][0] = q0;
            sA[pos][1] = q1;
            sA[pos][2] = q2;
            sF[pos]    = f;
        }
        __syncthreads();
        int n = sCnt;

        for (int s = 0; s < n; ++s) {
            float4 p0 = sA[s][0], p1 = sA[s][1], p2 = sA[s][2];
            int fi = sF[s];
            float w0x = fmaf(p0.x, x, p0.z);
            float w1x = fmaf(p0.w, x, p1.y);
            float w2x = fmaf(p1.z, x, p2.x);
            float zx  = fmaf(p2.y, x, p2.w);
            #pragma unroll
            for (int k = 0; k < 4; ++k) {
                float yk = y0 - (float)k * 0.03125f;   // 8 rows * 2/512
                float w0 = fmaf(p0.y, yk, w0x);
                float w1 = fmaf(p1.x, yk, w1x);
                float w2 = fmaf(p1.w, yk, w2x);
                float z  = fmaf(p2.z, yk, zx);
                bool hit = (fminf(fminf(w0, w1), w2) >= 0.0f) && (z > NEARZ);
                if (hit && z < bz[k]) { bz[k] = z; bi[k] = fi; }
            }
        }
    }

    #pragma unroll
    for (int k = 0; k < 4; ++k) {
        if (bi[k] >= 0) {
            int p = (row0 + 8*k) * IMG_W + colp;
            unsigned long long key =
                ((unsigned long long)__float_as_uint(bz[k]) << 32) | (unsigned)bi[k];
            atomicMin(&zbuf[p], key);
        }
    }
}

__global__ __launch_bounds__(256) void resolve_loss(
    const unsigned long long* __restrict__ zbuf,
    const float* __restrict__ cols,
    const float* __restrict__ imref,
    float* __restrict__ out)
{
    int p = blockIdx.x * 256 + threadIdx.x;
    unsigned long long key = zbuf[p];
    unsigned idx = (unsigned)(key & 0xffffffffull);
    float r = 0.0f, g = 0.0f, bl = 0.0f;
    if (idx != 0xffffffffu) {
        r  = cols[idx*3 + 0];
        g  = cols[idx*3 + 1];
        bl = cols[idx*3 + 2];
    }
    const int HW = IMG_H * IMG_W;
    // image[:, ::-1] reverses the CHANNEL axis
    float d0 = bl - imref[0*HW + p];
    float d1 = g  - imref[1*HW + p];
    float d2 = r  - imref[2*HW + p];
    float loss = fmaf(d0, d0, fmaf(d1, d1, d2*d2));

    #pragma unroll
    for (int off = 32; off > 0; off >>= 1)
        loss += __shfl_down(loss, off, 64);

    __shared__ float wsum[4];
    int wid  = threadIdx.x >> 6;
    int lane = threadIdx.x & 63;
    if (lane == 0) wsum[wid] = loss;
    __syncthreads();
    if (threadIdx.x == 0)
        atomicAdd(out, wsum[0] + wsum[1] + wsum[2] + wsum[3]);
}

// Fallback (small ws): Round-1 monolithic kernel, needs only fd+cols scratch.
__global__ __launch_bounds__(256) void raster_loss_mono(
    const float4* __restrict__ fd,
    const float* __restrict__ cols,
    const float* __restrict__ imref,
    float* __restrict__ out, int F)
{
    int p = blockIdx.x * 256 + threadIdx.x;
    int col = p & (IMG_W - 1);
    float x = ((float)col + 0.5f) * (2.0f / IMG_W) - 1.0f;
    float y = 1.0f - ((float)(p >> 9) + 0.5f) * (2.0f / IMG_H);

    float bestz = BIGF;
    int besti = -1;
    for (int f = 0; f < F; ++f) {
        float4 q0 = fd[3*f + 0];
        float4 q1 = fd[3*f + 1];
        float4 q2 = fd[3*f + 2];
        float w0 = fmaf(q0.x, x, fmaf(q0.y, y, q0.z));
        float w1 = fmaf(q0.w, x, fmaf(q1.x, y, q1.y));
        float w2 = fmaf(q1.z, x, fmaf(q1.w, y, q2.x));
        float z  = fmaf(q2.y, x, fmaf(q2.z, y, q2.w));
        bool hit = (w0 >= 0.0f) & (w1 >= 0.0f) & (w2 >= 0.0f) & (z > NEARZ);
        float zm = hit ? z : BIGF;
        if (zm < bestz) { bestz = zm; besti = f; }
    }
    float r = 0.0f, g = 0.0f, bl = 0.0f;
    if (besti >= 0) { r = cols[besti*3]; g = cols[besti*3+1]; bl = cols[besti*3+2]; }
    const int HW = IMG_H * IMG_W;
    float d0 = bl - imref[p], d1 = g - imref[HW+p], d2 = r - imref[2*HW+p];
    float loss = fmaf(d0, d0, fmaf(d1, d1, d2*d2));
    #pragma unroll
    for (int off = 32; off > 0; off >>= 1)
        loss += __shfl_down(loss, off, 64);
    __shared__ float wsum[4];
    int wid = threadIdx.x >> 6, lane = threadIdx.x & 63;
    if (lane == 0) wsum[wid] = loss;
    __syncthreads();
    if (threadIdx.x == 0)
        atomicAdd(out, wsum[0] + wsum[1] + wsum[2] + wsum[3]);
}

extern "C" void kernel_launch(void* const* d_in, const int* in_sizes, int n_in,
                              void* d_out, int out_size, void* d_ws, size_t ws_size,
                              hipStream_t stream)
{
    const float* verts  = (const float*)d_in[0];
    const int*   faces  = (const int*)d_in[1];
    const float* tex    = (const float*)d_in[2];
    const float* campos = (const float*)d_in[3];
    const float* camup  = (const float*)d_in[4];
    const float* imref  = (const float*)d_in[5];
    int F = in_sizes[1] / 3;

    const int P = IMG_H * IMG_W;
    size_t zbytes  = (size_t)P * 8;
    size_t fdbytes = (size_t)F * 3 * sizeof(float4);
    size_t cbytes  = (size_t)F * 3 * sizeof(float);
    float* out = (float*)d_out;

    hipMemsetAsync(d_out, 0, sizeof(float), stream);

    if (ws_size >= zbytes + fdbytes + cbytes) {
        unsigned long long* zbuf = (unsigned long long*)d_ws;
        float4* fd   = (float4*)((char*)d_ws + zbytes);
        float*  cols = (float*)((char*)d_ws + zbytes + fdbytes);

        hipMemsetAsync(zbuf, 0xFF, zbytes, stream);
        prep_faces<<<(F + 255)/256, 256, 0, stream>>>(verts, faces, tex, campos, camup, fd, cols, F);
        raster_tiled<<<NTILES * SPLITS, 256, 0, stream>>>(fd, F, zbuf);
        resolve_loss<<<P/256, 256, 0, stream>>>(zbuf, cols, imref, out);
    } else {
        float4* fd   = (float4*)d_ws;
        float*  cols = (float*)((char*)d_ws + fdbytes);
        prep_faces<<<(F + 255)/256, 256, 0, stream>>>(verts, faces, tex, campos, camup, fd, cols, F);
        raster_loss_mono<<<P/256, 256, 0, stream>>>(fd, cols, imref, out, F);
    }
}

// Round 3
// 119.805 us; speedup vs baseline: 9.8228x; 1.4532x over previous
//
#include <hip/hip_runtime.h>

#define IMG_H 512
#define IMG_W 512
#define VIEW_TAN_F 0.57735026918962576451f  // tan(30 deg)
#define NEARZ 0.1f
#define BIGF 1e10f

#define TILE 32
#define NTX (IMG_W / TILE)      // 16 tiles per row
#define NTILES (NTX * NTX)      // 256 tiles
#define RSPLITS 32              // blocks sharing one tile's face list (strided)
#define RCHUNK 256              // list entries staged to LDS per round

// Per-face data: 3 x float4 = {A0,B0,C0,A1},{B1,C1,A2,B2},{C2,Az,Bz,Cz}
// Edge coefficients premultiplied by sign(area): inside <=> w0,w1,w2 >= 0.
// z = Az*x + Bz*y + Cz (affine; division by area folded into coefficients).

__global__ void prep_faces(const float* __restrict__ verts,
                           const int* __restrict__ faces,
                           const float* __restrict__ tex,
                           const float* __restrict__ campos,
                           const float* __restrict__ camup,
                           float4* __restrict__ fd,
                           float* __restrict__ cols,
                           unsigned long long* __restrict__ zbuf,
                           int F)
{
    int gid = blockIdx.x * blockDim.x + threadIdx.x;

    // zbuf init (grid-stride), replaces a hipMemsetAsync dispatch
    if (zbuf) {
        const int P = IMG_H * IMG_W;
        for (int i = gid; i < P; i += gridDim.x * blockDim.x)
            zbuf[i] = ~0ull;
    }

    int f = gid;
    if (f >= F) return;

    float ex = campos[0], ey = campos[1], ez = campos[2];
    float ux = camup[0], uy = camup[1], uz = camup[2];
    float zxv = -ex, zyv = -ey, zzv = -ez;
    float inv = 1.0f / (sqrtf(zxv*zxv + zyv*zyv + zzv*zzv) + 1e-12f);
    zxv *= inv; zyv *= inv; zzv *= inv;
    inv = 1.0f / (sqrtf(ux*ux + uy*uy + uz*uz) + 1e-12f);
    ux *= inv; uy *= inv; uz *= inv;
    float xxv = uy*zzv - uz*zyv;
    float xyv = uz*zxv - ux*zzv;
    float xzv = ux*zyv - uy*zxv;
    inv = 1.0f / (sqrtf(xxv*xxv + xyv*xyv + xzv*xzv) + 1e-12f);
    xxv *= inv; xyv *= inv; xzv *= inv;
    float yxv = zyv*xzv - zzv*xyv;
    float yyv = zzv*xxv - zxv*xzv;
    float yzv = zxv*xyv - zyv*xxv;

    float px_[3], py_[3], pz_[3];
    #pragma unroll
    for (int k = 0; k < 3; ++k) {
        int vi = faces[f*3 + k];
        float vx = verts[vi*3+0] - ex;
        float vy = verts[vi*3+1] - ey;
        float vz = verts[vi*3+2] - ez;
        float cx = xxv*vx + xyv*vy + xzv*vz;
        float cy = yxv*vx + yyv*vy + yzv*vz;
        float cz = zxv*vx + zyv*vy + zzv*vz;
        float denom = cz * VIEW_TAN_F + 1e-12f;
        px_[k] = cx / denom;
        py_[k] = cy / denom;
        pz_[k] = cz;
    }
    float x0 = px_[0], y0 = py_[0];
    float x1 = px_[1], y1 = py_[1];
    float x2 = px_[2], y2 = py_[2];
    float area = (x1-x0)*(y2-y0) - (y1-y0)*(x2-x0);
    bool valid = fabsf(area) > 1e-8f;
    float safe = valid ? area : 1.0f;
    float s = (area > 0.0f) ? 1.0f : -1.0f;

    float A0 = -(y2-y1), B0 = (x2-x1), C0 = (y2-y1)*x1 - (x2-x1)*y1;
    float A1 = -(y0-y2), B1 = (x0-x2), C1 = (y0-y2)*x2 - (x0-x2)*y2;
    float A2 = -(y1-y0), B2 = (x1-x0), C2 = (y1-y0)*x0 - (x1-x0)*y0;

    float invs = 1.0f / safe;
    float Az = (A0*pz_[0] + A1*pz_[1] + A2*pz_[2]) * invs;
    float Bz = (B0*pz_[0] + B1*pz_[1] + B2*pz_[2]) * invs;
    float Cz = (C0*pz_[0] + C1*pz_[1] + C2*pz_[2]) * invs;

    A0 *= s; B0 *= s; C0 *= s;
    A1 *= s; B1 *= s; C1 *= s;
    A2 *= s; B2 *= s; C2 *= s;

    if (!valid) {
        A0 = B0 = A1 = B1 = A2 = B2 = 0.0f;
        C0 = C1 = C2 = -1.0f;   // always fails inside + tile tests
        Az = Bz = 0.0f; Cz = 0.0f;
    }

    fd[f*3+0] = make_float4(A0, B0, C0, A1);
    fd[f*3+1] = make_float4(B1, C1, A2, B2);
    fd[f*3+2] = make_float4(C2, Az, Bz, Cz);

    float c0 = 0.0f, c1 = 0.0f, c2 = 0.0f;
    #pragma unroll
    for (int t = 0; t < 8; ++t) {
        c0 += tex[f*24 + t*3 + 0];
        c1 += tex[f*24 + t*3 + 1];
        c2 += tex[f*24 + t*3 + 2];
    }
    cols[f*3+0] = c0 * 0.125f;
    cols[f*3+1] = c1 * 0.125f;
    cols[f*3+2] = c2 * 0.125f;
}

// One block per tile: conservative edge test vs tile rect, ballot-compact
// surviving face ids into the tile's global list.
__global__ __launch_bounds__(256) void bin_tiles(
    const float4* __restrict__ fd, int F,
    int* __restrict__ counts, int* __restrict__ lists)
{
    __shared__ int sCnt;
    int tile = blockIdx.x;
    int tX = tile & (NTX - 1);
    int tY = tile >> 4;
    int tid  = threadIdx.x;
    int lane = tid & 63;

    float cx = ((float)(tX * TILE + TILE/2)) * (2.0f / IMG_W) - 1.0f;
    float cy = 1.0f - ((float)(tY * TILE + TILE/2)) * (2.0f / IMG_H);
    const float hx = (TILE/2) * (2.0f / IMG_W);
    const float hy = (TILE/2) * (2.0f / IMG_H);

    if (tid == 0) sCnt = 0;
    __syncthreads();

    int* mylist = lists + (size_t)tile * F;
    for (int c0f = 0; c0f < F; c0f += 256) {
        int f = c0f + tid;
        bool pass = false;
        if (f < F) {
            float4 q0 = fd[3*f + 0];
            float4 q1 = fd[3*f + 1];
            float4 q2 = fd[3*f + 2];
            float e0 = fmaf(q0.x, cx, fmaf(q0.y, cy, q0.z)) + fabsf(q0.x)*hx + fabsf(q0.y)*hy;
            float e1 = fmaf(q0.w, cx, fmaf(q1.x, cy, q1.y)) + fabsf(q0.w)*hx + fabsf(q1.x)*hy;
            float e2 = fmaf(q1.z, cx, fmaf(q1.w, cy, q2.x)) + fabsf(q1.z)*hx + fabsf(q1.w)*hy;
            pass = fminf(fminf(e0, e1), e2) >= -1e-6f;
        }
        unsigned long long m = __ballot(pass);
        int wbase = 0;
        if (lane == 0 && m) wbase = atomicAdd(&sCnt, __popcll(m));
        wbase = __shfl(wbase, 0, 64);
        if (pass) {
            int pos = wbase + __popcll(m & ((1ull << lane) - 1ull));
            mylist[pos] = f;
        }
    }
    __syncthreads();
    if (tid == 0) counts[tile] = sCnt;
}

// (tile, split) blocks: split j processes list entries j, j+RSPLITS, ...
// Entries staged to LDS in rounds; inner loop = R2's validated 4px/thread core.
__global__ __launch_bounds__(256) void raster_binned(
    const float4* __restrict__ fd,
    const int* __restrict__ counts, const int* __restrict__ lists, int F,
    unsigned long long* __restrict__ zbuf)
{
    __shared__ float4 sA[RCHUNK][3];
    __shared__ int    sFi[RCHUNK];

    int b     = blockIdx.x;
    int split = b & (RSPLITS - 1);
    int tile  = b >> 5;                  // log2(RSPLITS)
    int n = counts[tile];
    int total_j = (n > split) ? ((n - split + RSPLITS - 1) / RSPLITS) : 0;
    if (total_j == 0) return;

    int tX = tile & (NTX - 1);
    int tY = tile >> 4;
    int tid = threadIdx.x;

    int colp = tX * TILE + (tid & 31);
    int row0 = tY * TILE + (tid >> 5);   // rows row0 + 8k, k=0..3
    float x  = ((float)colp + 0.5f) * (2.0f / IMG_W) - 1.0f;
    float y0 = 1.0f - ((float)row0 + 0.5f) * (2.0f / IMG_H);

    float bz[4] = {BIGF, BIGF, BIGF, BIGF};
    int   bi[4] = {-1, -1, -1, -1};

    const int* mylist = lists + (size_t)tile * F;

    for (int j0 = 0; j0 < total_j; j0 += RCHUNK) {
        int m = min(RCHUNK, total_j - j0);
        __syncthreads();                 // previous round's LDS fully consumed
        if (tid < m) {
            int e  = split + RSPLITS * (j0 + tid);
            int fi = mylist[e];
            sFi[tid]  = fi;
            sA[tid][0] = fd[3*fi + 0];
            sA[tid][1] = fd[3*fi + 1];
            sA[tid][2] = fd[3*fi + 2];
        }
        __syncthreads();

        for (int s = 0; s < m; ++s) {
            float4 p0 = sA[s][0], p1 = sA[s][1], p2 = sA[s][2];
            int fi = sFi[s];
            float w0x = fmaf(p0.x, x, p0.z);
            float w1x = fmaf(p0.w, x, p1.y);
            float w2x = fmaf(p1.z, x, p2.x);
            float zx  = fmaf(p2.y, x, p2.w);
            #pragma unroll
            for (int k = 0; k < 4; ++k) {
                float yk = y0 - (float)k * 0.03125f;   // 8 rows * 2/512
                float w0 = fmaf(p0.y, yk, w0x);
                float w1 = fmaf(p1.x, yk, w1x);
                float w2 = fmaf(p1.w, yk, w2x);
                float z  = fmaf(p2.z, yk, zx);
                bool hit = (fminf(fminf(w0, w1), w2) >= 0.0f) && (z > NEARZ);
                if (hit && z < bz[k]) { bz[k] = z; bi[k] = fi; }
            }
        }
    }

    #pragma unroll
    for (int k = 0; k < 4; ++k) {
        if (bi[k] >= 0) {
            int p = (row0 + 8*k) * IMG_W + colp;
            unsigned long long key =
                ((unsigned long long)__float_as_uint(bz[k]) << 32) | (unsigned)bi[k];
            atomicMin(&zbuf[p], key);
        }
    }
}

__global__ __launch_bounds__(256) void resolve_loss(
    const unsigned long long* __restrict__ zbuf,
    const float* __restrict__ cols,
    const float* __restrict__ imref,
    float* __restrict__ out)
{
    int p = blockIdx.x * 256 + threadIdx.x;
    unsigned long long key = zbuf[p];
    unsigned idx = (unsigned)(key & 0xffffffffull);
    float r = 0.0f, g = 0.0f, bl = 0.0f;
    if (idx != 0xffffffffu) {
        r  = cols[idx*3 + 0];
        g  = cols[idx*3 + 1];
        bl = cols[idx*3 + 2];
    }
    const int HW = IMG_H * IMG_W;
    // image[:, ::-1] reverses the CHANNEL axis
    float d0 = bl - imref[0*HW + p];
    float d1 = g  - imref[1*HW + p];
    float d2 = r  - imref[2*HW + p];
    float loss = fmaf(d0, d0, fmaf(d1, d1, d2*d2));

    #pragma unroll
    for (int off = 32; off > 0; off >>= 1)
        loss += __shfl_down(loss, off, 64);

    __shared__ float wsum[4];
    int wid  = threadIdx.x >> 6;
    int lane = threadIdx.x & 63;
    if (lane == 0) wsum[wid] = loss;
    __syncthreads();
    if (threadIdx.x == 0)
        atomicAdd(out, wsum[0] + wsum[1] + wsum[2] + wsum[3]);
}

// Fallback (small ws): Round-1 monolithic kernel (validated absmax 0).
__global__ __launch_bounds__(256) void raster_loss_mono(
    const float4* __restrict__ fd,
    const float* __restrict__ cols,
    const float* __restrict__ imref,
    float* __restrict__ out, int F)
{
    int p = blockIdx.x * 256 + threadIdx.x;
    int col = p & (IMG_W - 1);
    float x = ((float)col + 0.5f) * (2.0f / IMG_W) - 1.0f;
    float y = 1.0f - ((float)(p >> 9) + 0.5f) * (2.0f / IMG_H);

    float bestz = BIGF;
    int besti = -1;
    for (int f = 0; f < F; ++f) {
        float4 q0 = fd[3*f + 0];
        float4 q1 = fd[3*f + 1];
        float4 q2 = fd[3*f + 2];
        float w0 = fmaf(q0.x, x, fmaf(q0.y, y, q0.z));
        float w1 = fmaf(q0.w, x, fmaf(q1.x, y, q1.y));
        float w2 = fmaf(q1.z, x, fmaf(q1.w, y, q2.x));
        float z  = fmaf(q2.y, x, fmaf(q2.z, y, q2.w));
        bool hit = (w0 >= 0.0f) & (w1 >= 0.0f) & (w2 >= 0.0f) & (z > NEARZ);
        float zm = hit ? z : BIGF;
        if (zm < bestz) { bestz = zm; besti = f; }
    }
    float r = 0.0f, g = 0.0f, bl = 0.0f;
    if (besti >= 0) { r = cols[besti*3]; g = cols[besti*3+1]; bl = cols[besti*3+2]; }
    const int HW = IMG_H * IMG_W;
    float d0 = bl - imref[p], d1 = g - imref[HW+p], d2 = r - imref[2*HW+p];
    float loss = fmaf(d0, d0, fmaf(d1, d1, d2*d2));
    #pragma unroll
    for (int off = 32; off > 0; off >>= 1)
        loss += __shfl_down(loss, off, 64);
    __shared__ float wsum[4];
    int wid = threadIdx.x >> 6, lane = threadIdx.x & 63;
    if (lane == 0) wsum[wid] = loss;
    __syncthreads();
    if (threadIdx.x == 0)
        atomicAdd(out, wsum[0] + wsum[1] + wsum[2] + wsum[3]);
}

extern "C" void kernel_launch(void* const* d_in, const int* in_sizes, int n_in,
                              void* d_out, int out_size, void* d_ws, size_t ws_size,
                              hipStream_t stream)
{
    const float* verts  = (const float*)d_in[0];
    const int*   faces  = (const int*)d_in[1];
    const float* tex    = (const float*)d_in[2];
    const float* campos = (const float*)d_in[3];
    const float* camup  = (const float*)d_in[4];
    const float* imref  = (const float*)d_in[5];
    int F = in_sizes[1] / 3;

    const int P = IMG_H * IMG_W;
    size_t zbytes  = (size_t)P * 8;
    size_t cntB    = (size_t)NTILES * 4;
    size_t listB   = (size_t)NTILES * F * 4;
    size_t fdbytes = (size_t)F * 3 * sizeof(float4);
    size_t cbytes  = (size_t)F * 3 * sizeof(float);
    float* out = (float*)d_out;

    hipMemsetAsync(d_out, 0, sizeof(float), stream);

    if (ws_size >= zbytes + cntB + listB + fdbytes + cbytes) {
        char* w = (char*)d_ws;
        unsigned long long* zbuf = (unsigned long long*)w;          w += zbytes;
        int*    cnts = (int*)w;                                     w += cntB;
        int*    lst  = (int*)w;                                     w += listB;
        float4* fd   = (float4*)w;                                  w += fdbytes;
        float*  cols = (float*)w;

        int pgrid = (F + 255)/256 > 64 ? (F + 255)/256 : 64;  // extra blocks speed zbuf init
        prep_faces<<<pgrid, 256, 0, stream>>>(verts, faces, tex, campos, camup, fd, cols, zbuf, F);
        bin_tiles<<<NTILES, 256, 0, stream>>>(fd, F, cnts, lst);
        raster_binned<<<NTILES * RSPLITS, 256, 0, stream>>>(fd, cnts, lst, F, zbuf);
        resolve_loss<<<P/256, 256, 0, stream>>>(zbuf, cols, imref, out);
    } else {
        float4* fd   = (float4*)d_ws;
        float*  cols = (float*)((char*)d_ws + fdbytes);
        prep_faces<<<(F + 255)/256, 256, 0, stream>>>(verts, faces, tex, campos, camup, fd, cols,
                                                      (unsigned long long*)nullptr, F);
        raster_loss_mono<<<P/256, 256, 0, stream>>>(fd, cols, imref, out, F);
    }
}